// Round 1
// baseline (561.496 us; speedup 1.0000x reference)
//
#include <hip/hip_runtime.h>

typedef __attribute__((ext_vector_type(8))) short bf16x8;
typedef __attribute__((ext_vector_type(4))) float f32x4;

#define SL 2048
#define DM 768
#define NCH 32
#define MSPEC 24576   /* 32*768 */
#define MTOT  26880   /* 24576 + 3*768 */

__device__ __forceinline__ short f2bf(float f) {
  unsigned u = __builtin_bit_cast(unsigned, f);
  u = (u + 0x7FFFu + ((u >> 16) & 1u)) >> 16;
  return (short)u;
}

// ---------------- prep kernels ----------------

__global__ __launch_bounds__(256) void k_zero(float4* out) {
  out[blockIdx.x * 256 + threadIdx.x] = float4{0.f, 0.f, 0.f, 0.f};
}

// xT[d][l] = bf16(x[l][d])   (768 x 2048), LDS tiled transpose
__global__ __launch_bounds__(256) void k_prep_xT(const float* __restrict__ x,
                                                 short* __restrict__ xT) {
  __shared__ short tile[64][65];
  const int d0 = blockIdx.x * 64, l0 = blockIdx.y * 64;
  const int t = threadIdx.x;
#pragma unroll
  for (int rr = 0; rr < 16; ++rr) {
    int ll = rr * 4 + (t >> 6), dl = t & 63;
    tile[ll][dl] = f2bf(x[(size_t)(l0 + ll) * DM + d0 + dl]);
  }
  __syncthreads();
#pragma unroll
  for (int rr = 0; rr < 16; ++rr) {
    int dl = rr * 4 + (t >> 6), ll = t & 63;
    xT[(size_t)(d0 + dl) * SL + l0 + ll] = tile[ll][dl];
  }
}

// AR columns of U: U[l][24576 + i*768 + d] = x[l-i][d] (0 if l<i)
__global__ __launch_bounds__(256) void k_prep_ar(const float* __restrict__ x,
                                                 short* __restrict__ U) {
  int id = blockIdx.x * 256 + threadIdx.x;   // over 2048*768
  int l = id / DM, d = id - l * DM;
#pragma unroll
  for (int i = 0; i < 3; ++i) {
    short v = 0;
    if (l >= i) v = f2bf(x[(size_t)(l - i) * DM + d]);
    U[(size_t)l * MTOT + MSPEC + i * DM + d] = v;
  }
}

// Tmat[c][dlag][a][b] = f_c[dlag*128 + a - b]
__global__ __launch_bounds__(256) void k_prep_T(const float* __restrict__ phi,
                                                short* __restrict__ Tmat) {
  int idx = blockIdx.x * 256 + threadIdx.x;  // 32*16*128*128
  int b = idx & 127, a = (idx >> 7) & 127, dlag = (idx >> 14) & 15, c = idx >> 18;
  int j = dlag * 128 + a - b;
  short v = 0;
  if (j >= 0) {
    float p = phi[j * 16 + (c & 15)];
    if (c >= 16 && (j & 1)) p = -p;
    v = f2bf(p);
  }
  Tmat[idx] = v;
}

// McatT[o][m] (768 x 26880): m<24576 -> sigma^(1/4)-scaled M_phi_plus/minus; else M_u
__global__ __launch_bounds__(256) void k_prep_M(const float* __restrict__ Mp,
                                                const float* __restrict__ Mm,
                                                const float* __restrict__ Mu,
                                                const float* __restrict__ sigma,
                                                short* __restrict__ McatT) {
  __shared__ short tile[64][65];
  const int m0 = blockIdx.x * 64, o0 = blockIdx.y * 64;
  const int t = threadIdx.x;
#pragma unroll
  for (int rr = 0; rr < 16; ++rr) {
    int ml = rr * 4 + (t >> 6), ol = t & 63;
    int m = m0 + ml, o = o0 + ol;
    float v;
    if (m < MSPEC) {
      int c = m / DM, d = m - c * DM;
      int k = c & 15;
      float s4 = sqrtf(sqrtf(sigma[k]));
      if (c < 16) v = Mp[((size_t)c * DM + d) * DM + o] * s4;
      else        v = Mm[((size_t)(c - 16) * DM + d) * DM + o] * s4;
    } else {
      int mm = m - MSPEC;
      int i = mm / DM, d = mm - i * DM;
      v = Mu[((size_t)i * DM + d) * DM + o];
    }
    tile[ml][ol] = f2bf(v);
  }
  __syncthreads();
#pragma unroll
  for (int rr = 0; rr < 16; ++rr) {
    int ol = rr * 4 + (t >> 6), ml = t & 63;
    McatT[(size_t)(o0 + ol) * MTOT + m0 + ml] = tile[ml][ol];
  }
}

// ---------------- GEMM 1: block-Toeplitz conv ----------------
// grid (dtile 6, iblock 16, c 32); out tile U[i*128+a][c*768 + d0 + d]
__global__ __launch_bounds__(256) void k_gemm1(const short* __restrict__ Tmat,
                                               const short* __restrict__ xT,
                                               short* __restrict__ U) {
  __shared__ short As[128 * 40];
  __shared__ short Bs[128 * 40];
  const int dtile = blockIdx.x, ib = blockIdx.y, c = blockIdx.z;
  const int t = threadIdx.x;
  const int lane = t & 63, wave = t >> 6;
  const int wm = (wave >> 1) * 64, wn = (wave & 1) * 64;
  const int lrow = lane & 15, quad = lane >> 4;
  const int sr = t >> 1, sc = (t & 1) * 16;
  f32x4 acc[4][4] = {};
  const short* Abase = Tmat + ((size_t)(c * 16) << 14);
  const short* Bbase = xT + (size_t)dtile * 128 * SL;
  for (int dlag = 0; dlag <= ib; ++dlag) {
    const short* Ad = Abase + ((size_t)dlag << 14);
    const short* Bd = Bbase + (ib - dlag) * 128;
#pragma unroll
    for (int kk = 0; kk < 4; ++kk) {
      __syncthreads();
      {
        const int4* s = reinterpret_cast<const int4*>(Ad + sr * 128 + kk * 32 + sc);
        int4 v0 = s[0], v1 = s[1];
        int4* dst = reinterpret_cast<int4*>(&As[sr * 40 + sc]);
        dst[0] = v0; dst[1] = v1;
      }
      {
        const int4* s = reinterpret_cast<const int4*>(Bd + (size_t)sr * SL + kk * 32 + sc);
        int4 v0 = s[0], v1 = s[1];
        int4* dst = reinterpret_cast<int4*>(&Bs[sr * 40 + sc]);
        dst[0] = v0; dst[1] = v1;
      }
      __syncthreads();
      bf16x8 af[4], bfr[4];
#pragma unroll
      for (int im = 0; im < 4; ++im)
        af[im] = *reinterpret_cast<const bf16x8*>(&As[(wm + im * 16 + lrow) * 40 + quad * 8]);
#pragma unroll
      for (int in = 0; in < 4; ++in)
        bfr[in] = *reinterpret_cast<const bf16x8*>(&Bs[(wn + in * 16 + lrow) * 40 + quad * 8]);
#pragma unroll
      for (int im = 0; im < 4; ++im)
#pragma unroll
        for (int in = 0; in < 4; ++in)
          acc[im][in] = __builtin_amdgcn_mfma_f32_16x16x32_bf16(af[im], bfr[in], acc[im][in], 0, 0, 0);
    }
  }
  const int l0 = ib * 128, colbase = c * DM + dtile * 128;
#pragma unroll
  for (int im = 0; im < 4; ++im)
#pragma unroll
    for (int in = 0; in < 4; ++in)
#pragma unroll
      for (int r4 = 0; r4 < 4; ++r4) {
        int row = wm + im * 16 + quad * 4 + r4;
        int col = wn + in * 16 + lrow;
        U[(size_t)(l0 + row) * MTOT + colbase + col] = f2bf(acc[im][in][r4]);
      }
}

// ---------------- GEMM 2: projection + AR, split-K=8, atomic accumulate ----------------
// grid (otile 6, lblock 16, kc 8)
__global__ __launch_bounds__(256) void k_gemm2(const short* __restrict__ U,
                                               const short* __restrict__ McatT,
                                               float* __restrict__ out) {
  __shared__ short As[128 * 40];
  __shared__ short Bs[128 * 40];
  const int otile = blockIdx.x, lb = blockIdx.y, kc = blockIdx.z;
  const int t = threadIdx.x;
  const int lane = t & 63, wave = t >> 6;
  const int wm = (wave >> 1) * 64, wn = (wave & 1) * 64;
  const int lrow = lane & 15, quad = lane >> 4;
  const int sr = t >> 1, sc = (t & 1) * 16;
  f32x4 acc[4][4] = {};
  const short* Abase = U + (size_t)lb * 128 * MTOT + kc * 3360;
  const short* Bbase = McatT + (size_t)otile * 128 * MTOT + kc * 3360;
  for (int s = 0; s < 105; ++s) {
    __syncthreads();
    {
      const int4* sp = reinterpret_cast<const int4*>(Abase + (size_t)sr * MTOT + s * 32 + sc);
      int4 v0 = sp[0], v1 = sp[1];
      int4* dst = reinterpret_cast<int4*>(&As[sr * 40 + sc]);
      dst[0] = v0; dst[1] = v1;
    }
    {
      const int4* sp = reinterpret_cast<const int4*>(Bbase + (size_t)sr * MTOT + s * 32 + sc);
      int4 v0 = sp[0], v1 = sp[1];
      int4* dst = reinterpret_cast<int4*>(&Bs[sr * 40 + sc]);
      dst[0] = v0; dst[1] = v1;
    }
    __syncthreads();
    bf16x8 af[4], bfr[4];
#pragma unroll
    for (int im = 0; im < 4; ++im)
      af[im] = *reinterpret_cast<const bf16x8*>(&As[(wm + im * 16 + lrow) * 40 + quad * 8]);
#pragma unroll
    for (int in = 0; in < 4; ++in)
      bfr[in] = *reinterpret_cast<const bf16x8*>(&Bs[(wn + in * 16 + lrow) * 40 + quad * 8]);
#pragma unroll
    for (int im = 0; im < 4; ++im)
#pragma unroll
      for (int in = 0; in < 4; ++in)
        acc[im][in] = __builtin_amdgcn_mfma_f32_16x16x32_bf16(af[im], bfr[in], acc[im][in], 0, 0, 0);
  }
  const int l0 = lb * 128, o0 = otile * 128;
#pragma unroll
  for (int im = 0; im < 4; ++im)
#pragma unroll
    for (int in = 0; in < 4; ++in)
#pragma unroll
      for (int r4 = 0; r4 < 4; ++r4) {
        int row = wm + im * 16 + quad * 4 + r4;
        int col = wn + in * 16 + lrow;
        atomicAdd(&out[(size_t)(l0 + row) * DM + o0 + col], acc[im][in][r4]);
      }
}

extern "C" void kernel_launch(void* const* d_in, const int* in_sizes, int n_in,
                              void* d_out, int out_size, void* d_ws, size_t ws_size,
                              hipStream_t stream) {
  (void)in_sizes; (void)n_in; (void)out_size; (void)ws_size;
  const float* x     = (const float*)d_in[0];
  const float* phi   = (const float*)d_in[1];
  const float* sigma = (const float*)d_in[2];
  const float* Mp    = (const float*)d_in[3];
  const float* Mm    = (const float*)d_in[4];
  const float* Mu    = (const float*)d_in[5];
  float* out = (float*)d_out;
  char* ws = (char*)d_ws;

  short* U     = (short*)(ws);                    // 2048*26880*2   = 110,100,480
  short* Tmat  = (short*)(ws + 110100480);        // 32*16*128*128*2 = 16,777,216
  short* xT    = (short*)(ws + 126877696);        // 768*2048*2     = 3,145,728
  short* McatT = (short*)(ws + 130023424);        // 768*26880*2    = 41,287,680

  k_zero<<<dim3(1536), dim3(256), 0, stream>>>((float4*)out);
  k_prep_xT<<<dim3(12, 32), dim3(256), 0, stream>>>(x, xT);
  k_prep_ar<<<dim3(6144), dim3(256), 0, stream>>>(x, U);
  k_prep_T<<<dim3(32768), dim3(256), 0, stream>>>(phi, Tmat);
  k_prep_M<<<dim3(420, 12), dim3(256), 0, stream>>>(Mp, Mm, Mu, sigma, McatT);
  k_gemm1<<<dim3(6, 16, 32), dim3(256), 0, stream>>>(Tmat, xT, U);
  k_gemm2<<<dim3(6, 16, 8), dim3(256), 0, stream>>>(U, McatT, out);
}

// Round 2
// 493.203 us; speedup vs baseline: 1.1385x; 1.1385x over previous
//
#include <hip/hip_runtime.h>

typedef __attribute__((ext_vector_type(8))) short bf16x8;
typedef __attribute__((ext_vector_type(4))) float f32x4;

#define SL 2048
#define DM 768
#define NCH 32
#define MSPEC 24576   /* 32*768 */
#define MTOT  26880   /* 24576 + 3*768 */

__device__ __forceinline__ short f2bf(float f) {
  unsigned u = __builtin_bit_cast(unsigned, f);
  u = (u + 0x7FFFu + ((u >> 16) & 1u)) >> 16;
  return (short)u;
}

// async global->LDS, 16B per lane. LDS dest is wave-linear: base + lane*16.
__device__ __forceinline__ void gload16(const short* g, short* l) {
  __builtin_amdgcn_global_load_lds(
      (const __attribute__((address_space(1))) void*)g,
      (__attribute__((address_space(3))) void*)l, 16, 0, 0);
}

// ---------------- prep kernels ----------------

__global__ __launch_bounds__(256) void k_zero(float4* out) {
  out[blockIdx.x * 256 + threadIdx.x] = float4{0.f, 0.f, 0.f, 0.f};
}

// xT[d][l] = bf16(x[l][d])   (768 x 2048), LDS tiled transpose
__global__ __launch_bounds__(256) void k_prep_xT(const float* __restrict__ x,
                                                 short* __restrict__ xT) {
  __shared__ short tile[64][65];
  const int d0 = blockIdx.x * 64, l0 = blockIdx.y * 64;
  const int t = threadIdx.x;
#pragma unroll
  for (int rr = 0; rr < 16; ++rr) {
    int ll = rr * 4 + (t >> 6), dl = t & 63;
    tile[ll][dl] = f2bf(x[(size_t)(l0 + ll) * DM + d0 + dl]);
  }
  __syncthreads();
#pragma unroll
  for (int rr = 0; rr < 16; ++rr) {
    int dl = rr * 4 + (t >> 6), ll = t & 63;
    xT[(size_t)(d0 + dl) * SL + l0 + ll] = tile[ll][dl];
  }
}

// AR columns of U: U[l][24576 + i*768 + d] = x[l-i][d] (0 if l<i)
__global__ __launch_bounds__(256) void k_prep_ar(const float* __restrict__ x,
                                                 short* __restrict__ U) {
  int id = blockIdx.x * 256 + threadIdx.x;   // over 2048*768
  int l = id / DM, d = id - l * DM;
#pragma unroll
  for (int i = 0; i < 3; ++i) {
    short v = 0;
    if (l >= i) v = f2bf(x[(size_t)(l - i) * DM + d]);
    U[(size_t)l * MTOT + MSPEC + i * DM + d] = v;
  }
}

// Tmat[c][dlag][a][b] = f_c[dlag*128 + a - b]
__global__ __launch_bounds__(256) void k_prep_T(const float* __restrict__ phi,
                                                short* __restrict__ Tmat) {
  int idx = blockIdx.x * 256 + threadIdx.x;  // 32*16*128*128
  int b = idx & 127, a = (idx >> 7) & 127, dlag = (idx >> 14) & 15, c = idx >> 18;
  int j = dlag * 128 + a - b;
  short v = 0;
  if (j >= 0) {
    float p = phi[j * 16 + (c & 15)];
    if (c >= 16 && (j & 1)) p = -p;
    v = f2bf(p);
  }
  Tmat[idx] = v;
}

// McatT[o][m] (768 x 26880): m<24576 -> sigma^(1/4)-scaled M_phi_plus/minus; else M_u
__global__ __launch_bounds__(256) void k_prep_M(const float* __restrict__ Mp,
                                                const float* __restrict__ Mm,
                                                const float* __restrict__ Mu,
                                                const float* __restrict__ sigma,
                                                short* __restrict__ McatT) {
  __shared__ short tile[64][65];
  const int m0 = blockIdx.x * 64, o0 = blockIdx.y * 64;
  const int t = threadIdx.x;
#pragma unroll
  for (int rr = 0; rr < 16; ++rr) {
    int ml = rr * 4 + (t >> 6), ol = t & 63;
    int m = m0 + ml, o = o0 + ol;
    float v;
    if (m < MSPEC) {
      int c = m / DM, d = m - c * DM;
      int k = c & 15;
      float s4 = sqrtf(sqrtf(sigma[k]));
      if (c < 16) v = Mp[((size_t)c * DM + d) * DM + o] * s4;
      else        v = Mm[((size_t)(c - 16) * DM + d) * DM + o] * s4;
    } else {
      int mm = m - MSPEC;
      int i = mm / DM, d = mm - i * DM;
      v = Mu[((size_t)i * DM + d) * DM + o];
    }
    tile[ml][ol] = f2bf(v);
  }
  __syncthreads();
#pragma unroll
  for (int rr = 0; rr < 16; ++rr) {
    int ol = rr * 4 + (t >> 6), ml = t & 63;
    McatT[(size_t)(o0 + ol) * MTOT + m0 + ml] = tile[ml][ol];
  }
}

// ---------------- GEMM 1: block-Toeplitz conv (m97-style staging) ----------------
// grid (dtile 6, iblock 16, c 32); out tile U[i*128+a][c*768 + d0 + d]
__global__ __launch_bounds__(256) void k_gemm1(const short* __restrict__ Tmat,
                                               const short* __restrict__ xT,
                                               short* __restrict__ U) {
  __shared__ __align__(16) short As[128 * 32];
  __shared__ __align__(16) short Bs[128 * 32];
  const int dtile = blockIdx.x, ib = 15 - (int)blockIdx.y, c = blockIdx.z;
  const int t = threadIdx.x;
  const int lane = t & 63, wave = t >> 6;
  const int wm = (wave >> 1) * 64, wn = (wave & 1) * 64;
  const int lrow = lane & 15, quad = lane >> 4;
  const int l4 = lane >> 2, lq = lane & 3;
  // staging: wave covers rows [wave*32, wave*32+32) in 2 sections of 16 rows
  const int r0 = wave * 32 + l4;
  const int swz = (lq ^ ((l4 >> 1) & 3)) * 8;        // shorts, same for both sections
  short* lA = &As[wave * 1024 + lane * 8];
  short* lB = &Bs[wave * 1024 + lane * 8];
  // fragment read swizzle (wave-invariant per lane)
  const int foff = ((quad ^ ((lrow >> 1) & 3)) << 3);

  f32x4 acc[4][4] = {};
  const short* Abase = Tmat + ((size_t)(c * 16) << 14);
  const short* Bbase = xT + (size_t)dtile * 128 * SL;
  for (int dlag = 0; dlag <= ib; ++dlag) {
    const short* Ad = Abase + ((size_t)dlag << 14) + r0 * 128 + swz;
    const short* Bd = Bbase + (size_t)r0 * SL + (ib - dlag) * 128 + swz;
#pragma unroll
    for (int kk = 0; kk < 4; ++kk) {
      __syncthreads();
      gload16(Ad + kk * 32, lA);
      gload16(Ad + kk * 32 + 16 * 128, lA + 512);
      gload16(Bd + kk * 32, lB);
      gload16(Bd + kk * 32 + 16 * SL, lB + 512);
      __syncthreads();
      bf16x8 af[4], bfr[4];
#pragma unroll
      for (int im = 0; im < 4; ++im)
        af[im] = *reinterpret_cast<const bf16x8*>(&As[(wm + im * 16 + lrow) * 32 + foff]);
#pragma unroll
      for (int in = 0; in < 4; ++in)
        bfr[in] = *reinterpret_cast<const bf16x8*>(&Bs[(wn + in * 16 + lrow) * 32 + foff]);
#pragma unroll
      for (int im = 0; im < 4; ++im)
#pragma unroll
        for (int in = 0; in < 4; ++in)
          acc[im][in] = __builtin_amdgcn_mfma_f32_16x16x32_bf16(af[im], bfr[in], acc[im][in], 0, 0, 0);
    }
  }
  const int l0 = ib * 128, colbase = c * DM + dtile * 128;
#pragma unroll
  for (int im = 0; im < 4; ++im)
#pragma unroll
    for (int in = 0; in < 4; ++in)
#pragma unroll
      for (int r4 = 0; r4 < 4; ++r4) {
        int row = wm + im * 16 + quad * 4 + r4;
        int col = wn + in * 16 + lrow;
        U[(size_t)(l0 + row) * MTOT + colbase + col] = f2bf(acc[im][in][r4]);
      }
}

// ---------------- GEMM 2: projection + AR, split-K=8, atomic accumulate ----------------
// grid (otile 6, lblock 16, kc 8)
__global__ __launch_bounds__(256) void k_gemm2(const short* __restrict__ U,
                                               const short* __restrict__ McatT,
                                               float* __restrict__ out) {
  __shared__ __align__(16) short As[128 * 32];
  __shared__ __align__(16) short Bs[128 * 32];
  const int otile = blockIdx.x, lb = blockIdx.y, kc = blockIdx.z;
  const int t = threadIdx.x;
  const int lane = t & 63, wave = t >> 6;
  const int wm = (wave >> 1) * 64, wn = (wave & 1) * 64;
  const int lrow = lane & 15, quad = lane >> 4;
  const int l4 = lane >> 2, lq = lane & 3;
  const int r0 = wave * 32 + l4;
  const int swz = (lq ^ ((l4 >> 1) & 3)) * 8;
  short* lA = &As[wave * 1024 + lane * 8];
  short* lB = &Bs[wave * 1024 + lane * 8];
  const int foff = ((quad ^ ((lrow >> 1) & 3)) << 3);

  f32x4 acc[4][4] = {};
  const short* Ad = U + (size_t)lb * 128 * MTOT + kc * 3360 + (size_t)r0 * MTOT + swz;
  const short* Bd = McatT + (size_t)otile * 128 * MTOT + kc * 3360 + (size_t)r0 * MTOT + swz;
  for (int s = 0; s < 105; ++s) {
    __syncthreads();
    gload16(Ad + s * 32, lA);
    gload16(Ad + s * 32 + (size_t)16 * MTOT, lA + 512);
    gload16(Bd + s * 32, lB);
    gload16(Bd + s * 32 + (size_t)16 * MTOT, lB + 512);
    __syncthreads();
    bf16x8 af[4], bfr[4];
#pragma unroll
    for (int im = 0; im < 4; ++im)
      af[im] = *reinterpret_cast<const bf16x8*>(&As[(wm + im * 16 + lrow) * 32 + foff]);
#pragma unroll
    for (int in = 0; in < 4; ++in)
      bfr[in] = *reinterpret_cast<const bf16x8*>(&Bs[(wn + in * 16 + lrow) * 32 + foff]);
#pragma unroll
    for (int im = 0; im < 4; ++im)
#pragma unroll
      for (int in = 0; in < 4; ++in)
        acc[im][in] = __builtin_amdgcn_mfma_f32_16x16x32_bf16(af[im], bfr[in], acc[im][in], 0, 0, 0);
  }
  const int l0 = lb * 128, o0 = otile * 128;
#pragma unroll
  for (int im = 0; im < 4; ++im)
#pragma unroll
    for (int in = 0; in < 4; ++in)
#pragma unroll
      for (int r4 = 0; r4 < 4; ++r4) {
        int row = wm + im * 16 + quad * 4 + r4;
        int col = wn + in * 16 + lrow;
        atomicAdd(&out[(size_t)(l0 + row) * DM + o0 + col], acc[im][in][r4]);
      }
}

extern "C" void kernel_launch(void* const* d_in, const int* in_sizes, int n_in,
                              void* d_out, int out_size, void* d_ws, size_t ws_size,
                              hipStream_t stream) {
  (void)in_sizes; (void)n_in; (void)out_size; (void)ws_size;
  const float* x     = (const float*)d_in[0];
  const float* phi   = (const float*)d_in[1];
  const float* sigma = (const float*)d_in[2];
  const float* Mp    = (const float*)d_in[3];
  const float* Mm    = (const float*)d_in[4];
  const float* Mu    = (const float*)d_in[5];
  float* out = (float*)d_out;
  char* ws = (char*)d_ws;

  short* U     = (short*)(ws);                    // 2048*26880*2   = 110,100,480
  short* Tmat  = (short*)(ws + 110100480);        // 32*16*128*128*2 = 16,777,216
  short* xT    = (short*)(ws + 126877696);        // 768*2048*2     = 3,145,728
  short* McatT = (short*)(ws + 130023424);        // 768*26880*2    = 41,287,680

  k_zero<<<dim3(1536), dim3(256), 0, stream>>>((float4*)out);
  k_prep_xT<<<dim3(12, 32), dim3(256), 0, stream>>>(x, xT);
  k_prep_ar<<<dim3(6144), dim3(256), 0, stream>>>(x, U);
  k_prep_T<<<dim3(32768), dim3(256), 0, stream>>>(phi, Tmat);
  k_prep_M<<<dim3(420, 12), dim3(256), 0, stream>>>(Mp, Mm, Mu, sigma, McatT);
  k_gemm1<<<dim3(6, 16, 32), dim3(256), 0, stream>>>(Tmat, xT, U);
  k_gemm2<<<dim3(6, 16, 8), dim3(256), 0, stream>>>(U, McatT, out);
}

// Round 3
// 416.871 us; speedup vs baseline: 1.3469x; 1.1831x over previous
//
#include <hip/hip_runtime.h>

typedef __attribute__((ext_vector_type(8))) short bf16x8;
typedef __attribute__((ext_vector_type(4))) float f32x4;

#define SL 2048
#define DM 768
#define NCH 32
#define MSPEC 24576   /* 32*768 */
#define MTOT  26880   /* 24576 + 3*768 */

__device__ __forceinline__ short f2bf(float f) {
  unsigned u = __builtin_bit_cast(unsigned, f);
  u = (u + 0x7FFFu + ((u >> 16) & 1u)) >> 16;
  return (short)u;
}

// async global->LDS, 16B per lane. LDS dest must be wave-uniform base + lane*16.
__device__ __forceinline__ void gload16(const short* g, short* l) {
  __builtin_amdgcn_global_load_lds(
      (const __attribute__((address_space(1))) void*)g,
      (__attribute__((address_space(3))) void*)l, 16, 0, 0);
}

// ---------------- prep kernels ----------------

__global__ __launch_bounds__(256) void k_zero(float4* out) {
  out[blockIdx.x * 256 + threadIdx.x] = float4{0.f, 0.f, 0.f, 0.f};
}

// xT[d][l] = bf16(x[l][d])   (768 x 2048), LDS tiled transpose
__global__ __launch_bounds__(256) void k_prep_xT(const float* __restrict__ x,
                                                 short* __restrict__ xT) {
  __shared__ short tile[64][65];
  const int d0 = blockIdx.x * 64, l0 = blockIdx.y * 64;
  const int t = threadIdx.x;
#pragma unroll
  for (int rr = 0; rr < 16; ++rr) {
    int ll = rr * 4 + (t >> 6), dl = t & 63;
    tile[ll][dl] = f2bf(x[(size_t)(l0 + ll) * DM + d0 + dl]);
  }
  __syncthreads();
#pragma unroll
  for (int rr = 0; rr < 16; ++rr) {
    int dl = rr * 4 + (t >> 6), ll = t & 63;
    xT[(size_t)(d0 + dl) * SL + l0 + ll] = tile[ll][dl];
  }
}

// AR columns of U: U[l][24576 + i*768 + d] = x[l-i][d] (0 if l<i)
__global__ __launch_bounds__(256) void k_prep_ar(const float* __restrict__ x,
                                                 short* __restrict__ U) {
  int id = blockIdx.x * 256 + threadIdx.x;   // over 2048*768
  int l = id / DM, d = id - l * DM;
#pragma unroll
  for (int i = 0; i < 3; ++i) {
    short v = 0;
    if (l >= i) v = f2bf(x[(size_t)(l - i) * DM + d]);
    U[(size_t)l * MTOT + MSPEC + i * DM + d] = v;
  }
}

// Tmat[c][dlag][a][b] = f_c[dlag*128 + a - b]
__global__ __launch_bounds__(256) void k_prep_T(const float* __restrict__ phi,
                                                short* __restrict__ Tmat) {
  int idx = blockIdx.x * 256 + threadIdx.x;  // 32*16*128*128
  int b = idx & 127, a = (idx >> 7) & 127, dlag = (idx >> 14) & 15, c = idx >> 18;
  int j = dlag * 128 + a - b;
  short v = 0;
  if (j >= 0) {
    float p = phi[j * 16 + (c & 15)];
    if (c >= 16 && (j & 1)) p = -p;
    v = f2bf(p);
  }
  Tmat[idx] = v;
}

// McatT[o][m] (768 x 26880): m<24576 -> sigma^(1/4)-scaled M_phi_plus/minus; else M_u
__global__ __launch_bounds__(256) void k_prep_M(const float* __restrict__ Mp,
                                                const float* __restrict__ Mm,
                                                const float* __restrict__ Mu,
                                                const float* __restrict__ sigma,
                                                short* __restrict__ McatT) {
  __shared__ short tile[64][65];
  const int m0 = blockIdx.x * 64, o0 = blockIdx.y * 64;
  const int t = threadIdx.x;
#pragma unroll
  for (int rr = 0; rr < 16; ++rr) {
    int ml = rr * 4 + (t >> 6), ol = t & 63;
    int m = m0 + ml, o = o0 + ol;
    float v;
    if (m < MSPEC) {
      int c = m / DM, d = m - c * DM;
      int k = c & 15;
      float s4 = sqrtf(sqrtf(sigma[k]));
      if (c < 16) v = Mp[((size_t)c * DM + d) * DM + o] * s4;
      else        v = Mm[((size_t)(c - 16) * DM + d) * DM + o] * s4;
    } else {
      int mm = m - MSPEC;
      int i = mm / DM, d = mm - i * DM;
      v = Mu[((size_t)i * DM + d) * DM + o];
    }
    tile[ml][ol] = f2bf(v);
  }
  __syncthreads();
#pragma unroll
  for (int rr = 0; rr < 16; ++rr) {
    int ol = rr * 4 + (t >> 6), ml = t & 63;
    McatT[(size_t)(o0 + ol) * MTOT + m0 + ml] = tile[ml][ol];
  }
}

// ---------------- GEMM 1: block-Toeplitz conv, double-buffered, XCD-swizzled ----------------
// 1D grid 3072: xcd = wid&7 owns 4 channels; big-ib blocks first.
__global__ __launch_bounds__(256) void k_gemm1(const short* __restrict__ Tmat,
                                               const short* __restrict__ xT,
                                               short* __restrict__ U) {
  __shared__ __align__(16) short As[2][128 * 32];
  __shared__ __align__(16) short Bs[2][128 * 32];
  const int wid = blockIdx.x;
  const int xcd = wid & 7;
  const int slot = wid >> 3;                 // 0..383
  const int c = xcd * 4 + (slot & 3);        // 4 channels per XCD -> Tmat L2-resident
  const int dtile = (slot >> 2) % 6;
  const int ib = 15 - (slot >> 2) / 6;       // big (triangular) blocks first
  const int t = threadIdx.x;
  const int lane = t & 63, wave = t >> 6;
  const int wm = (wave >> 1) * 64, wn = (wave & 1) * 64;
  const int lrow = lane & 15, quad = lane >> 4;
  const int l4 = lane >> 2, lq = lane & 3;
  const int r0 = wave * 32 + l4;
  const int swz = (lq ^ ((l4 >> 1) & 3)) * 8;
  const int foff = ((quad ^ ((lrow >> 1) & 3)) << 3);

  f32x4 acc[4][4] = {};
  const short* Abase = Tmat + ((size_t)(c * 16) << 14) + r0 * 128 + swz;
  const short* Bbase = xT + (size_t)dtile * 128 * SL + (size_t)r0 * SL + swz;
  const int nit = 4 * (ib + 1);

  auto stage = [&](int it, int buf) {
    int dlag = it >> 2, kk = it & 3;
    const short* Ad = Abase + ((size_t)dlag << 14) + kk * 32;
    const short* Bd = Bbase + (ib - dlag) * 128 + kk * 32;
    short* lA = &As[buf][wave * 1024 + lane * 8];
    short* lB = &Bs[buf][wave * 1024 + lane * 8];
    gload16(Ad, lA);
    gload16(Ad + 16 * 128, lA + 512);
    gload16(Bd, lB);
    gload16(Bd + 16 * SL, lB + 512);
  };

  stage(0, 0);
  int cur = 0;
  for (int it = 0; it < nit; ++it) {
    __syncthreads();                      // drains prefetch into buf 'cur'
    if (it + 1 < nit) stage(it + 1, cur ^ 1);
    bf16x8 af[4], bfr[4];
#pragma unroll
    for (int im = 0; im < 4; ++im)
      af[im] = *reinterpret_cast<const bf16x8*>(&As[cur][(wm + im * 16 + lrow) * 32 + foff]);
#pragma unroll
    for (int in = 0; in < 4; ++in)
      bfr[in] = *reinterpret_cast<const bf16x8*>(&Bs[cur][(wn + in * 16 + lrow) * 32 + foff]);
#pragma unroll
    for (int im = 0; im < 4; ++im)
#pragma unroll
      for (int in = 0; in < 4; ++in)
        acc[im][in] = __builtin_amdgcn_mfma_f32_16x16x32_bf16(af[im], bfr[in], acc[im][in], 0, 0, 0);
    cur ^= 1;
  }
  const int l0 = ib * 128, colbase = c * DM + dtile * 128;
#pragma unroll
  for (int im = 0; im < 4; ++im)
#pragma unroll
    for (int in = 0; in < 4; ++in)
#pragma unroll
      for (int r4 = 0; r4 < 4; ++r4) {
        int row = wm + im * 16 + quad * 4 + r4;
        int col = wn + in * 16 + lrow;
        U[(size_t)(l0 + row) * MTOT + colbase + col] = f2bf(acc[im][in][r4]);
      }
}

// ---------------- GEMM 2: projection + AR, split-K=8 (1 kc per XCD), dbuf ----------------
// 1D grid 768: kc = wid&7 -> each XCD owns one K-slice (B-slice L2-resident)
__global__ __launch_bounds__(256) void k_gemm2(const short* __restrict__ U,
                                               const short* __restrict__ McatT,
                                               float* __restrict__ out) {
  __shared__ __align__(16) short As[2][128 * 32];
  __shared__ __align__(16) short Bs[2][128 * 32];
  const int wid = blockIdx.x;
  const int kc = wid & 7;
  const int slot = wid >> 3;                 // 0..95
  const int otile = slot % 6;
  const int lb = slot / 6;
  const int t = threadIdx.x;
  const int lane = t & 63, wave = t >> 6;
  const int wm = (wave >> 1) * 64, wn = (wave & 1) * 64;
  const int lrow = lane & 15, quad = lane >> 4;
  const int l4 = lane >> 2, lq = lane & 3;
  const int r0 = wave * 32 + l4;
  const int swz = (lq ^ ((l4 >> 1) & 3)) * 8;
  const int foff = ((quad ^ ((lrow >> 1) & 3)) << 3);

  f32x4 acc[4][4] = {};
  const short* Ab = U + (size_t)lb * 128 * MTOT + kc * 3360 + (size_t)r0 * MTOT + swz;
  const short* Bb = McatT + (size_t)otile * 128 * MTOT + kc * 3360 + (size_t)r0 * MTOT + swz;

  auto stage = [&](int s, int buf) {
    short* lA = &As[buf][wave * 1024 + lane * 8];
    short* lB = &Bs[buf][wave * 1024 + lane * 8];
    gload16(Ab + s * 32, lA);
    gload16(Ab + s * 32 + (size_t)16 * MTOT, lA + 512);
    gload16(Bb + s * 32, lB);
    gload16(Bb + s * 32 + (size_t)16 * MTOT, lB + 512);
  };

  stage(0, 0);
  int cur = 0;
  for (int s = 0; s < 105; ++s) {
    __syncthreads();
    if (s + 1 < 105) stage(s + 1, cur ^ 1);
    bf16x8 af[4], bfr[4];
#pragma unroll
    for (int im = 0; im < 4; ++im)
      af[im] = *reinterpret_cast<const bf16x8*>(&As[cur][(wm + im * 16 + lrow) * 32 + foff]);
#pragma unroll
    for (int in = 0; in < 4; ++in)
      bfr[in] = *reinterpret_cast<const bf16x8*>(&Bs[cur][(wn + in * 16 + lrow) * 32 + foff]);
#pragma unroll
    for (int im = 0; im < 4; ++im)
#pragma unroll
      for (int in = 0; in < 4; ++in)
        acc[im][in] = __builtin_amdgcn_mfma_f32_16x16x32_bf16(af[im], bfr[in], acc[im][in], 0, 0, 0);
    cur ^= 1;
  }
  const int l0 = lb * 128, o0 = otile * 128;
#pragma unroll
  for (int im = 0; im < 4; ++im)
#pragma unroll
    for (int in = 0; in < 4; ++in)
#pragma unroll
      for (int r4 = 0; r4 < 4; ++r4) {
        int row = wm + im * 16 + quad * 4 + r4;
        int col = wn + in * 16 + lrow;
        atomicAdd(&out[(size_t)(l0 + row) * DM + o0 + col], acc[im][in][r4]);
      }
}

extern "C" void kernel_launch(void* const* d_in, const int* in_sizes, int n_in,
                              void* d_out, int out_size, void* d_ws, size_t ws_size,
                              hipStream_t stream) {
  (void)in_sizes; (void)n_in; (void)out_size; (void)ws_size;
  const float* x     = (const float*)d_in[0];
  const float* phi   = (const float*)d_in[1];
  const float* sigma = (const float*)d_in[2];
  const float* Mp    = (const float*)d_in[3];
  const float* Mm    = (const float*)d_in[4];
  const float* Mu    = (const float*)d_in[5];
  float* out = (float*)d_out;
  char* ws = (char*)d_ws;

  short* U     = (short*)(ws);                    // 2048*26880*2   = 110,100,480
  short* Tmat  = (short*)(ws + 110100480);        // 32*16*128*128*2 = 16,777,216
  short* xT    = (short*)(ws + 126877696);        // 768*2048*2     = 3,145,728
  short* McatT = (short*)(ws + 130023424);        // 768*26880*2    = 41,287,680

  k_zero<<<dim3(1536), dim3(256), 0, stream>>>((float4*)out);
  k_prep_xT<<<dim3(12, 32), dim3(256), 0, stream>>>(x, xT);
  k_prep_ar<<<dim3(6144), dim3(256), 0, stream>>>(x, U);
  k_prep_T<<<dim3(32768), dim3(256), 0, stream>>>(phi, Tmat);
  k_prep_M<<<dim3(420, 12), dim3(256), 0, stream>>>(Mp, Mm, Mu, sigma, McatT);
  k_gemm1<<<dim3(3072), dim3(256), 0, stream>>>(Tmat, xT, U);
  k_gemm2<<<dim3(768), dim3(256), 0, stream>>>(U, McatT, out);
}